// Round 14
// baseline (242.154 us; speedup 1.0000x reference)
//
#include <hip/hip_runtime.h>
#include <cstdint>

constexpr int Sd = 1024;
constexpr int Td = 48;
constexpr int NTAG = 45;    // normal tags 0..44
constexpr int START_ = 45;
constexpr int STOP_ = 46;

__device__ __forceinline__ int rfl_i(int x) { return __builtin_amdgcn_readfirstlane(x); }

// DPP-fused MAC: acc += rot(s, N) * ee   (rotation folded into the FMA)
#define FMD(acc, s, ee, N) \
    asm("v_fmac_f32 %0, %1, %2 row_ror:" #N " row_mask:0xf bank_mask:0xf" \
        : "+v"(acc) : "v"(s), "v"(ee))
// DPP-fused MUL (chain init): acc = rot(s, N) * ee
#define MULD(acc, s, ee, N) \
    asm("v_mul_f32 %0, %1, %2 row_ror:" #N " row_mask:0xf bank_mask:0xf" \
        : "=v"(acc) : "v"(s), "v"(ee))

// 16 rotations of one slot dotted with its E block; two 8-deep chains
#define SLOT16(s, E, aA, aB) do {                                              \
    aA = (s) * E[0];                                                           \
    FMD(aA, s, E[1], 1);  FMD(aA, s, E[2], 2);  FMD(aA, s, E[3], 3);           \
    FMD(aA, s, E[4], 4);  FMD(aA, s, E[5], 5);  FMD(aA, s, E[6], 6);           \
    FMD(aA, s, E[7], 7);                                                       \
    MULD(aB, s, E[8], 8);                                                      \
    FMD(aB, s, E[9], 9);  FMD(aB, s, E[10], 10); FMD(aB, s, E[11], 11);        \
    FMD(aB, s, E[12], 12); FMD(aB, s, E[13], 13); FMD(aB, s, E[14], 14);       \
    FMD(aB, s, E[15], 15);                                                     \
} while (0)

// One exp-domain chain step (R12-validated, 57 VALU instrs):
//   slot0 = vv; slot1/2 = ds_bpermute vv[(lane+16/32)%48]
//   48 DPP-fused MACs vs shared eE0/eE1/eE2; PF pre-exp'd;
//   scalar power-of-2 renorm via readfirstlane (exact).
#define STEPC(vv, uff, kxx, scc, LL, PF) do {                                  \
    int _vi = __float_as_int(vv);                                              \
    int _b1 = __builtin_amdgcn_ds_bpermute(a16, _vi);                          \
    int _b2 = __builtin_amdgcn_ds_bpermute(a32, _vi);                          \
    float _s1 = __int_as_float(_b1), _s2 = __int_as_float(_b2);                \
    float a0A, a0B, a1A, a1B, a2A, a2B;                                        \
    SLOT16(vv,  eE0, a0A, a0B);                                                \
    SLOT16(_s1, eE1, a1A, a1B);                                                \
    SLOT16(_s2, eE2, a2A, a2B);                                                \
    float tot_ = ((a0A + a0B) + (a1A + a1B)) + (a2A + a2B);                    \
    LL += kxx;                                                                 \
    uff = tot_ * scc;                                                          \
    vv = tot_ * ((PF) * scc);                                                  \
    { int _kb = rfl_i(__float_as_int(vv));                                     \
      kxx = ((_kb >> 23) & 0xFF) - 127;                                        \
      scc = __int_as_float((127 - kxx) << 23); }                               \
} while (0)

#define ADVA() do { bool ok_ = isb ? (tnA > 0) : (tnA < Sd - 1);               \
    pcA += ok_ ? sAdv : 0; tnA += ok_ ? sInc : 0; } while (0)
#define ADVB() do { bool ok_ = isb ? (tnB > 0) : (tnB < Sd - 1);               \
    pcB += ok_ ? sAdv : 0; tnB += ok_ ? sInc : 0; } while (0)
#define ADVT() do { bool ok_ = isb ? (tnT > 0) : (tnT < Sd - 1);               \
    pcT += ok_ ? sAdv : 0; tnT += ok_ ? sInc : 0; } while (0)

__launch_bounds__(64)
__global__ void crf_chains(const float* __restrict__ feats,
                           const float* __restrict__ masks,
                           const int* __restrict__ tags,
                           const float* __restrict__ trans,
                           float* __restrict__ wsv,   // [48][Bn] fwd meeting vec
                           float* __restrict__ wsu,   // [48][Bn] bwd meeting vec
                           int* __restrict__ wsLF, int* __restrict__ wsLB,
                           float* __restrict__ wsg,   // [Bn] gold
                           int Bn)
{
    __shared__ float tl[Td * Td];
    const int lane = threadIdx.x;
    const int nPair = Bn >> 1;
    const bool isb = ((int)blockIdx.x >= nPair);     // block-uniform direction
    const int pair = isb ? ((int)blockIdx.x - nPair) : (int)blockIdx.x;
    const int bA = pair * 2, bB = bA + 1;

    for (int i = lane; i < Td * Td; i += 64) tl[i] = trans[i];
    __syncthreads();

    const size_t bSA = (size_t)bA * Sd;
    const size_t bSB = (size_t)bB * Sd;

    // ---- lengths (scalar) ----
    auto get_len = [&](size_t bS) {
        float c = 0.f;
        for (int t = lane; t < Sd; t += 64) c += masks[bS + t];
#pragma unroll
        for (int off = 32; off; off >>= 1) c += __shfl_xor(c, off);
        int l = (int)(c + 0.5f);
        return rfl_i(l < 1 ? 1 : l);
    };
    const int lenA = get_len(bSA);
    const int lenB = get_len(bSB);

    // ---- gold scores (fwd blocks only) ----
    if (!isb) {
        auto get_gold = [&](size_t bS, int len) {
            float g = 0.f;
            for (int t = lane; t < len; t += 64) {
                const int tag  = tags[bS + t];
                const int prev = (t == 0) ? START_ : tags[bS + t - 1];
                g += feats[(bS + t) * Td + tag] + tl[tag * Td + prev];
            }
#pragma unroll
            for (int off = 32; off; off >>= 1) g += __shfl_xor(g, off);
            return g + tl[STOP_ * Td + tags[bS + len - 1]];
        };
        const float gA = get_gold(bSA, lenA);
        const float gB = get_gold(bSB, lenB);
        if (lane == 0) { wsg[bA] = gA; wsg[bB] = gB; }
    }

    // ---- runtime-detect row_ror direction (validated R9-R12) ----
    const int p = lane & 15;
    const int qd = __builtin_amdgcn_mov_dpp(p, 0x121, 0xF, 0xF, false); // row_ror:1
    const int d = (qd == ((p + 1) & 15)) ? 1 : -1;
    const int r0 = (lane >> 4) & 3;

    // ---- bpermute byte-addresses for the 3-block rotation gather ----
    const int a16 = (((lane + 16) % Td) << 2);
    const int a32 = (((lane + 32) % Td) << 2);

    // ---- ONE direction's matrix, gather-permuted scalar order (48 regs) ----
    float eE0[16], eE1[16], eE2[16];
#pragma unroll
    for (int h = 0; h < 3; ++h) {
        float* dst = (h == 0) ? eE0 : (h == 1) ? eE1 : eE2;
        const int blk = 16 * ((r0 + h) % 3);
#pragma unroll
        for (int i = 0; i < 16; ++i) {
            const int cc = blk + ((p + d * i) & 15);
            float e0 = 0.f;
            if (!isb) { if (lane < NTAG) e0 = __expf(tl[lane * Td + cc]); }
            else      { if (lane < Td)   e0 = __expf(tl[cc * Td + lane]); }
            dst[i] = e0;
        }
    }

    // ---- chain inits ----
    const int lidx = (lane < Td) ? lane : 0;
    const float* frowA = feats + bSA * Td;
    const float* frowB = feats + bSB * Td;
    const int FhA = (lenA + 1) >> 1, FhB = (lenB + 1) >> 1;
    const int actA = rfl_i(isb ? (lenA - FhA) : (FhA - 1));
    const int actB = rfl_i(isb ? (lenB - FhB) : (FhB - 1));

    float einit;
    if (!isb) einit = (lane < NTAG) ? __expf(tl[lane * Td + START_]) : 0.f;
    else      einit = (lane < Td)   ? __expf(tl[STOP_ * Td + lane])  : 0.f;

    const int itA = isb ? (lenA - 1) : 0;
    const int itB = isb ? (lenB - 1) : 0;
    float vA = __expf(frowA[(size_t)itA * Td + lidx]) * einit;
    float vB = __expf(frowB[(size_t)itB * Td + lidx]) * einit;
    float ufA = einit, ufB = einit;                  // bwd act==0 case: wstop
    int LA = 0, LB = 0, kxA, kxB; float scA, scB;
    { int kb = rfl_i(__float_as_int(vA)); kxA = ((kb >> 23) & 0xFF) - 127;
      scA = __int_as_float((127 - kxA) << 23); }
    { int kb = rfl_i(__float_as_int(vB)); kxB = ((kb >> 23) & 0xFF) - 127;
      scB = __int_as_float((127 - kxB) << 23); }

    // ---- emission prefetch: 4 slots/chain, PRE-EXP'd; scalar advance ----
    auto eiA = [&](int s) -> int {
        if (isb) { int t = lenA - 2 - s; return t > 0 ? t : 0; }
        int t = 1 + s; return t < Sd ? t : (Sd - 1);
    };
    auto eiB = [&](int s) -> int {
        if (isb) { int t = lenB - 2 - s; return t > 0 ? t : 0; }
        int t = 1 + s; return t < Sd ? t : (Sd - 1);
    };
    float pfA0 = __expf(frowA[(size_t)eiA(0) * Td + lidx]);
    float pfA1 = __expf(frowA[(size_t)eiA(1) * Td + lidx]);
    float pfA2 = __expf(frowA[(size_t)eiA(2) * Td + lidx]);
    float pfA3 = __expf(frowA[(size_t)eiA(3) * Td + lidx]);
    float pfB0 = __expf(frowB[(size_t)eiB(0) * Td + lidx]);
    float pfB1 = __expf(frowB[(size_t)eiB(1) * Td + lidx]);
    float pfB2 = __expf(frowB[(size_t)eiB(2) * Td + lidx]);
    float pfB3 = __expf(frowB[(size_t)eiB(3) * Td + lidx]);
    int tnA = eiA(4), tnB = eiB(4);
    const float* pcA = frowA + (size_t)tnA * Td;
    const float* pcB = frowB + (size_t)tnB * Td;
    const int sAdv = isb ? -Td : Td;
    const int sInc = isb ? -1 : 1;

    // ---- common supersteps: predicate-free interleave of 2 chains ----
    const int common = actA < actB ? actA : actB;
    int k = 0;
    while (k + 4 <= common) {
        STEPC(vA, ufA, kxA, scA, LA, pfA0); STEPC(vB, ufB, kxB, scB, LB, pfB0);
        pfA0 = __expf(pcA[lidx]); ADVA();   pfB0 = __expf(pcB[lidx]); ADVB();
        STEPC(vA, ufA, kxA, scA, LA, pfA1); STEPC(vB, ufB, kxB, scB, LB, pfB1);
        pfA1 = __expf(pcA[lidx]); ADVA();   pfB1 = __expf(pcB[lidx]); ADVB();
        STEPC(vA, ufA, kxA, scA, LA, pfA2); STEPC(vB, ufB, kxB, scB, LB, pfB2);
        pfA2 = __expf(pcA[lidx]); ADVA();   pfB2 = __expf(pcB[lidx]); ADVB();
        STEPC(vA, ufA, kxA, scA, LA, pfA3); STEPC(vB, ufB, kxB, scB, LB, pfB3);
        pfA3 = __expf(pcA[lidx]); ADVA();   pfB3 = __expf(pcB[lidx]); ADVB();
        k += 4;
    }
    if (k < common) { STEPC(vA, ufA, kxA, scA, LA, pfA0); STEPC(vB, ufB, kxB, scB, LB, pfB0); ++k; }
    if (k < common) { STEPC(vA, ufA, kxA, scA, LA, pfA1); STEPC(vB, ufB, kxB, scB, LB, pfB1); ++k; }
    if (k < common) { STEPC(vA, ufA, kxA, scA, LA, pfA2); STEPC(vB, ufB, kxB, scB, LB, pfB2); ++k; }

    // ---- tail: single-chain, wave-uniform-selected registers ----
    const bool longA = actA > actB;
    const int actT = longA ? actA : actB;
    if (common < actT) {
        const float* frowT = longA ? frowA : frowB;
        const int lenT = longA ? lenA : lenB;
        float vT = longA ? vA : vB;
        float ufT = longA ? ufA : ufB;
        int kxT = longA ? kxA : kxB; float scT = longA ? scA : scB;
        int LT = longA ? LA : LB;
        auto eiT = [&](int s) -> int {
            if (isb) { int t = lenT - 2 - s; return t > 0 ? t : 0; }
            int t = 1 + s; return t < Sd ? t : (Sd - 1);
        };
        float pfT0 = __expf(frowT[(size_t)eiT(common + 0) * Td + lidx]);
        float pfT1 = __expf(frowT[(size_t)eiT(common + 1) * Td + lidx]);
        float pfT2 = __expf(frowT[(size_t)eiT(common + 2) * Td + lidx]);
        float pfT3 = __expf(frowT[(size_t)eiT(common + 3) * Td + lidx]);
        int tnT = eiT(common + 4);
        const float* pcT = frowT + (size_t)tnT * Td;
        int kT = common;
        while (kT + 4 <= actT) {
            STEPC(vT, ufT, kxT, scT, LT, pfT0); pfT0 = __expf(pcT[lidx]); ADVT();
            STEPC(vT, ufT, kxT, scT, LT, pfT1); pfT1 = __expf(pcT[lidx]); ADVT();
            STEPC(vT, ufT, kxT, scT, LT, pfT2); pfT2 = __expf(pcT[lidx]); ADVT();
            STEPC(vT, ufT, kxT, scT, LT, pfT3); pfT3 = __expf(pcT[lidx]); ADVT();
            kT += 4;
        }
        if (kT < actT) { STEPC(vT, ufT, kxT, scT, LT, pfT0); ++kT; }
        if (kT < actT) { STEPC(vT, ufT, kxT, scT, LT, pfT1); ++kT; }
        if (kT < actT) { STEPC(vT, ufT, kxT, scT, LT, pfT2); ++kT; }
        if (longA) { vA = vT; ufA = ufT; LA = LT; }
        else       { vB = vT; ufB = ufT; LB = LT; }
    }

    // ---- publish meeting pieces (component-major for coalesced combine) ----
    if (!isb) {
        if (lane < Td) { wsv[lane * Bn + bA] = vA; wsv[lane * Bn + bB] = vB; }
        if (lane == 0) { wsLF[bA] = LA; wsLF[bB] = LB; }
    } else {
        if (lane < Td) { wsu[lane * Bn + bA] = ufA; wsu[lane * Bn + bB] = ufB; }
        if (lane == 0) { wsLB[bA] = LA; wsLB[bB] = LB; }
    }
}

__launch_bounds__(64)
__global__ void crf_combine(const float* __restrict__ wsv,
                            const float* __restrict__ wsu,
                            const int* __restrict__ wsLF,
                            const int* __restrict__ wsLB,
                            const float* __restrict__ wsg,
                            float* __restrict__ out, int Bn)
{
    const int b = blockIdx.x * 64 + threadIdx.x;
    if (b >= Bn) return;
    float dot = 0.f;
#pragma unroll
    for (int j = 0; j < Td; ++j)
        dot += wsv[j * Bn + b] * wsu[j * Bn + b];
    const float ln2 = 0.6931471805599453f;
    out[b] = (float)(wsLF[b] + wsLB[b]) * ln2 + __logf(dot) - wsg[b];
}

extern "C" void kernel_launch(void* const* d_in, const int* in_sizes, int n_in,
                              void* d_out, int out_size, void* d_ws, size_t ws_size,
                              hipStream_t stream) {
    const float* feats = (const float*)d_in[0];
    const float* masks = (const float*)d_in[1];
    const int*   tags  = (const int*)d_in[2];
    const float* trans = (const float*)d_in[3];
    float* outp = (float*)d_out;

    const int Bn = in_sizes[1] / Sd;                 // B = 512

    float* wsv  = (float*)d_ws;                      // [48][Bn]
    float* wsu  = wsv + (size_t)Td * Bn;             // [48][Bn]
    int*   wsLF = (int*)(wsu + (size_t)Td * Bn);     // [Bn]
    int*   wsLB = wsLF + Bn;                         // [Bn]
    float* wsg  = (float*)(wsLB + Bn);               // [Bn]

    crf_chains<<<dim3(Bn), dim3(64), 0, stream>>>(feats, masks, tags, trans,
                                                  wsv, wsu, wsLF, wsLB, wsg, Bn);
    crf_combine<<<dim3((Bn + 63) / 64), dim3(64), 0, stream>>>(wsv, wsu, wsLF, wsLB, wsg, outp, Bn);
}

// Round 15
// 145.014 us; speedup vs baseline: 1.6699x; 1.6699x over previous
//
#include <hip/hip_runtime.h>
#include <cstdint>

constexpr int Sd = 1024;
constexpr int Td = 48;
constexpr int NTAG = 45;    // normal tags 0..44
constexpr int START_ = 45;
constexpr int STOP_ = 46;

__device__ __forceinline__ int rfl_i(int x) { return __builtin_amdgcn_readfirstlane(x); }

#define SWAP32(x, y) asm volatile("v_permlane32_swap_b32 %0, %1" : "+v"(x), "+v"(y))
#define SWAP16(x, y) asm volatile("v_permlane16_swap_b32 %0, %1" : "+v"(x), "+v"(y))

// DPP-fused MAC / MUL, order-pinned (volatile) for hand-interleaved chains
#define FMD(acc, s, ee, N) \
    asm volatile("v_fmac_f32 %0, %1, %2 row_ror:" #N " row_mask:0xf bank_mask:0xf" \
        : "+v"(acc) : "v"(s), "v"(ee))
#define MULD(acc, s, ee, N) \
    asm volatile("v_mul_f32 %0, %1, %2 row_ror:" #N " row_mask:0xf bank_mask:0xf" \
        : "=v"(acc) : "v"(s), "v"(ee))

// One exp-domain chain step (R12-validated arithmetic):
//   gather slots via permlane self-swaps (R10-validated dup semantics,
//   runtime-detected) + precomputed-mask cndmask selects (zero LDS);
//   48 DPP-fused MACs over 12 round-robin accumulator chains;
//   scalar power-of-2 renorm via readfirstlane (exact).
#define STEP1(PF) do {                                                         \
    int _A = __float_as_int(v), _B = __float_as_int(v);                        \
    SWAP32(_A, _B);                                                            \
    int _S0 = _A, _S1 = _A; SWAP16(_S0, _S1);                                  \
    int _S2 = _B, _S3 = _B; SWAP16(_S2, _S3);                                  \
    float _f0 = __int_as_float(_S0), _f1 = __int_as_float(_S1);                \
    float _f2 = __int_as_float(_S2), _f3 = __int_as_float(_S3);                \
    float _x1 = _f0; _x1 = q11 ? _f1 : _x1; _x1 = q12 ? _f2 : _x1;             \
    _x1 = q13 ? _f3 : _x1;                                                     \
    float _x2 = _f0; _x2 = q21 ? _f1 : _x2; _x2 = q22 ? _f2 : _x2;             \
    _x2 = q23 ? _f3 : _x2;                                                     \
    float z00, z01, z02, z03, z10, z11, z12, z13, z20, z21, z22, z23;          \
    z00 = v * eE0[0];                                                          \
    MULD(z01, v, eE0[1], 1); MULD(z02, v, eE0[2], 2); MULD(z03, v, eE0[3], 3); \
    FMD(z00, v, eE0[4], 4);  FMD(z01, v, eE0[5], 5);                           \
    FMD(z02, v, eE0[6], 6);  FMD(z03, v, eE0[7], 7);                           \
    FMD(z00, v, eE0[8], 8);  FMD(z01, v, eE0[9], 9);                           \
    FMD(z02, v, eE0[10], 10); FMD(z03, v, eE0[11], 11);                        \
    FMD(z00, v, eE0[12], 12); FMD(z01, v, eE0[13], 13);                        \
    FMD(z02, v, eE0[14], 14); FMD(z03, v, eE0[15], 15);                        \
    z10 = _x1 * eE1[0];       z20 = _x2 * eE2[0];                              \
    MULD(z11, _x1, eE1[1], 1);  MULD(z21, _x2, eE2[1], 1);                     \
    MULD(z12, _x1, eE1[2], 2);  MULD(z22, _x2, eE2[2], 2);                     \
    MULD(z13, _x1, eE1[3], 3);  MULD(z23, _x2, eE2[3], 3);                     \
    FMD(z10, _x1, eE1[4], 4);   FMD(z20, _x2, eE2[4], 4);                      \
    FMD(z11, _x1, eE1[5], 5);   FMD(z21, _x2, eE2[5], 5);                      \
    FMD(z12, _x1, eE1[6], 6);   FMD(z22, _x2, eE2[6], 6);                      \
    FMD(z13, _x1, eE1[7], 7);   FMD(z23, _x2, eE2[7], 7);                      \
    FMD(z10, _x1, eE1[8], 8);   FMD(z20, _x2, eE2[8], 8);                      \
    FMD(z11, _x1, eE1[9], 9);   FMD(z21, _x2, eE2[9], 9);                      \
    FMD(z12, _x1, eE1[10], 10); FMD(z22, _x2, eE2[10], 10);                    \
    FMD(z13, _x1, eE1[11], 11); FMD(z23, _x2, eE2[11], 11);                    \
    FMD(z10, _x1, eE1[12], 12); FMD(z20, _x2, eE2[12], 12);                    \
    FMD(z11, _x1, eE1[13], 13); FMD(z21, _x2, eE2[13], 13);                    \
    FMD(z12, _x1, eE1[14], 14); FMD(z22, _x2, eE2[14], 14);                    \
    FMD(z13, _x1, eE1[15], 15); FMD(z23, _x2, eE2[15], 15);                    \
    float tot_ = (((z00 + z01) + (z02 + z03)) + ((z10 + z11) + (z12 + z13)))   \
               + ((z20 + z21) + (z22 + z23));                                  \
    L += kx;                                                                   \
    uf = tot_ * sc;                                                            \
    v  = tot_ * ((PF) * sc);                                                   \
    { int _kb = rfl_i(__float_as_int(v));                                      \
      kx = ((_kb >> 23) & 0xFF) - 127;                                         \
      sc = __int_as_float((127 - kx) << 23); }                                 \
} while (0)

#define ADVP() do {                                                            \
    bool ok_ = isb ? (tn > 0) : (tn < tmax);                                   \
    pcur += ok_ ? sAdv : 0;                                                    \
    tn   += ok_ ? sInc : 0;                                                    \
} while (0)

__launch_bounds__(64, 1)
__global__ void crf_chains(const float* __restrict__ feats,
                           const float* __restrict__ masks,
                           const int* __restrict__ tags,
                           const float* __restrict__ trans,
                           float* __restrict__ wsv,   // [48][Bn] fwd meeting vec
                           float* __restrict__ wsu,   // [48][Bn] bwd meeting vec
                           int* __restrict__ wsLF, int* __restrict__ wsLB,
                           float* __restrict__ wsg,   // [Bn] gold
                           int Bn)
{
    __shared__ float tl[Td * Td];
    const int lane = threadIdx.x;
    const bool isb = ((int)blockIdx.x >= Bn);        // block-uniform direction
    const int b = isb ? ((int)blockIdx.x - Bn) : (int)blockIdx.x;

    for (int i = lane; i < Td * Td; i += 64) tl[i] = trans[i];
    __syncthreads();

    const size_t bS = (size_t)b * Sd;

    // ---- length from prefix mask (scalar) ----
    float c = 0.f;
    for (int t = lane; t < Sd; t += 64) c += masks[bS + t];
#pragma unroll
    for (int off = 32; off; off >>= 1) c += __shfl_xor(c, off);
    int len = (int)(c + 0.5f);
    if (len < 1) len = 1;
    len = rfl_i(len);

    // ---- gold score (fwd blocks only) ----
    if (!isb) {
        float g = 0.f;
        for (int t = lane; t < len; t += 64) {
            const int tag  = tags[bS + t];
            const int prev = (t == 0) ? START_ : tags[bS + t - 1];
            g += feats[(bS + t) * Td + tag] + tl[tag * Td + prev];
        }
#pragma unroll
        for (int off = 32; off; off >>= 1) g += __shfl_xor(g, off);
        g += tl[STOP_ * Td + tags[bS + len - 1]];
        if (lane == 0) wsg[b] = g;
    }

    // ---- runtime-detect DPP/permlane semantics (R9/R10-validated method) ----
    const int p = lane & 15;
    const int qd = __builtin_amdgcn_mov_dpp(p, 0x121, 0xF, 0xF, false); // row_ror:1
    const int d = (qd == ((p + 1) & 15)) ? 1 : -1;
    const int g16 = lane >> 4;
    const int r0 = g16 & 3;                          // own 16-block

    // marker through the swap pipeline -> which reg holds which block (full dup)
    int ma = lane, mb = lane;
    SWAP32(ma, mb);
    int m0 = ma, m1 = ma; SWAP16(m0, m1);
    int m2 = mb, m3 = mb; SWAP16(m2, m3);
    const int ro0 = rfl_i(m0) >> 4, ro1 = rfl_i(m1) >> 4;
    const int ro2 = rfl_i(m2) >> 4, ro3 = rfl_i(m3) >> 4;
    const int want1 = (g16 + 1) % 3;                 // slot1 block per lane group
    const int want2 = (g16 + 2) % 3;                 // slot2 block per lane group
    const bool q11 = (ro1 == want1), q12 = (ro2 == want1), q13 = (ro3 == want1);
    const bool q21 = (ro1 == want2), q22 = (ro2 == want2), q23 = (ro3 == want2);
    // base of selects is _f0; correct when ro0 == want (exactly one reg matches)
    (void)ro0;

    // ---- E (fwd) / E^T (bwd) in gather-permuted scalar order, 48 regs ----
    float eE0[16], eE1[16], eE2[16];
#pragma unroll
    for (int h = 0; h < 3; ++h) {
        float* dst = (h == 0) ? eE0 : (h == 1) ? eE1 : eE2;
        const int blk = 16 * ((r0 + h) % 3);
#pragma unroll
        for (int i = 0; i < 16; ++i) {
            const int cc = blk + ((p + d * i) & 15);
            float e0 = 0.f;
            if (!isb) { if (lane < NTAG) e0 = __expf(tl[lane * Td + cc]); }
            else      { if (lane < Td)   e0 = __expf(tl[cc * Td + lane]); }
            dst[i] = e0;
        }
    }
    // pin E into VGPRs: opaque pass-through blocks rematerialization
#pragma unroll
    for (int i = 0; i < 16; ++i)
        asm volatile("" : "+v"(eE0[i]), "+v"(eE1[i]), "+v"(eE2[i]));

    // ---- chain init ----
    const int lidx = (lane < Td) ? lane : 0;
    const float* frow = feats + bS * Td;
    const int Fh = (len + 1) >> 1;
    const int act = rfl_i(isb ? (len - Fh) : (Fh - 1));
    const int it0 = isb ? (len - 1) : 0;

    float einit;
    if (!isb) einit = (lane < NTAG) ? __expf(tl[lane * Td + START_]) : 0.f;
    else      einit = (lane < Td)   ? __expf(tl[STOP_ * Td + lane])  : 0.f;

    float v  = __expf(frow[(size_t)it0 * Td + lidx]) * einit;
    float uf = einit;                 // bwd act==0 case: wstop
    int L = 0, kx; float sc;
    { int kb = rfl_i(__float_as_int(v)); kx = ((kb >> 23) & 0xFF) - 127;
      sc = __int_as_float((127 - kx) << 23); }

    // ---- emission prefetch: 8 slots, PRE-EXP'd; uniform ptr + scalar advance ----
    auto eidx0 = [&](int s) -> int {
        if (!isb) { int t = 1 + s; return t < Sd ? t : (Sd - 1); }
        int t = len - 2 - s; return t > 0 ? t : 0;
    };
    float pf0 = __expf(frow[(size_t)eidx0(0) * Td + lidx]);
    float pf1 = __expf(frow[(size_t)eidx0(1) * Td + lidx]);
    float pf2 = __expf(frow[(size_t)eidx0(2) * Td + lidx]);
    float pf3 = __expf(frow[(size_t)eidx0(3) * Td + lidx]);
    float pf4 = __expf(frow[(size_t)eidx0(4) * Td + lidx]);
    float pf5 = __expf(frow[(size_t)eidx0(5) * Td + lidx]);
    float pf6 = __expf(frow[(size_t)eidx0(6) * Td + lidx]);
    float pf7 = __expf(frow[(size_t)eidx0(7) * Td + lidx]);
    int tn = eidx0(8);
    const float* pcur = frow + (size_t)tn * Td;
    const int sAdv = isb ? -Td : Td;
    const int sInc = isb ? -1 : 1;
    const int tmax = Sd - 1;

    int s = 0;
    while (s + 8 <= act) {
        STEP1(pf0); pf0 = __expf(pcur[lidx]); ADVP();
        STEP1(pf1); pf1 = __expf(pcur[lidx]); ADVP();
        STEP1(pf2); pf2 = __expf(pcur[lidx]); ADVP();
        STEP1(pf3); pf3 = __expf(pcur[lidx]); ADVP();
        STEP1(pf4); pf4 = __expf(pcur[lidx]); ADVP();
        STEP1(pf5); pf5 = __expf(pcur[lidx]); ADVP();
        STEP1(pf6); pf6 = __expf(pcur[lidx]); ADVP();
        STEP1(pf7); pf7 = __expf(pcur[lidx]); ADVP();
        s += 8;
    }
    if (s < act) { STEP1(pf0); ++s; }
    if (s < act) { STEP1(pf1); ++s; }
    if (s < act) { STEP1(pf2); ++s; }
    if (s < act) { STEP1(pf3); ++s; }
    if (s < act) { STEP1(pf4); ++s; }
    if (s < act) { STEP1(pf5); ++s; }
    if (s < act) { STEP1(pf6); ++s; }

    // ---- publish meeting pieces (component-major for coalesced combine) ----
    if (!isb) {
        if (lane < Td) wsv[lane * Bn + b] = v;
        if (lane == 0) wsLF[b] = L;
    } else {
        if (lane < Td) wsu[lane * Bn + b] = uf;
        if (lane == 0) wsLB[b] = L;
    }
}

__launch_bounds__(64)
__global__ void crf_combine(const float* __restrict__ wsv,
                            const float* __restrict__ wsu,
                            const int* __restrict__ wsLF,
                            const int* __restrict__ wsLB,
                            const float* __restrict__ wsg,
                            float* __restrict__ out, int Bn)
{
    const int b = blockIdx.x * 64 + threadIdx.x;
    if (b >= Bn) return;
    float dot = 0.f;
#pragma unroll
    for (int j = 0; j < Td; ++j)
        dot += wsv[j * Bn + b] * wsu[j * Bn + b];
    const float ln2 = 0.6931471805599453f;
    out[b] = (float)(wsLF[b] + wsLB[b]) * ln2 + __logf(dot) - wsg[b];
}

extern "C" void kernel_launch(void* const* d_in, const int* in_sizes, int n_in,
                              void* d_out, int out_size, void* d_ws, size_t ws_size,
                              hipStream_t stream) {
    const float* feats = (const float*)d_in[0];
    const float* masks = (const float*)d_in[1];
    const int*   tags  = (const int*)d_in[2];
    const float* trans = (const float*)d_in[3];
    float* outp = (float*)d_out;

    const int Bn = in_sizes[1] / Sd;                 // B = 512

    float* wsv  = (float*)d_ws;                      // [48][Bn]
    float* wsu  = wsv + (size_t)Td * Bn;             // [48][Bn]
    int*   wsLF = (int*)(wsu + (size_t)Td * Bn);     // [Bn]
    int*   wsLB = wsLF + Bn;                         // [Bn]
    float* wsg  = (float*)(wsLB + Bn);               // [Bn]

    crf_chains<<<dim3(2 * Bn), dim3(64), 0, stream>>>(feats, masks, tags, trans,
                                                      wsv, wsu, wsLF, wsLB, wsg, Bn);
    crf_combine<<<dim3((Bn + 63) / 64), dim3(64), 0, stream>>>(wsv, wsu, wsLF, wsLB, wsg, outp, Bn);
}